// Round 8
// baseline (662.386 us; speedup 1.0000x reference)
//
#include <hip/hip_runtime.h>
#include <stdint.h>

// Problem constants: B=8, N=4096, C=768, G=16, D=48
// qkv GEMM: M=32768, N=2304, K=768 ; proj GEMM: M=32768, N=768, K=768
//
// Toolchain facts (rounds 3-7): 512-thread blocks got VGPR-capped at 128 ->
// acc spill -> 2.8 GB scratch. 256-thread blocks allocate freely (236 seen).
// R7 analysis: B-through-LDS makes LDS the binding pipe (16 KiB staged + 32 KiB
// read per block-iter = 104 us floor for qkv). This round: B direct from L2 to
// registers (weights are L2-resident: 3.5 MB qkv / 1.2 MB proj), A-only LDS ring.

using short8 = __attribute__((__ext_vector_type__(8))) short;
using f32x4  = __attribute__((__ext_vector_type__(4))) float;

typedef const void __attribute__((address_space(1))) gv_t;
typedef void __attribute__((address_space(3))) lv_t;

__device__ __forceinline__ void gll16(const void* g, void* l) {
  __builtin_amdgcn_global_load_lds((gv_t*)g, (lv_t*)l, 16, 0, 0);
}

__device__ __forceinline__ uint16_t f2b(float f) {
  uint32_t x = __float_as_uint(f);
  uint32_t r = (x + 0x7fffu + ((x >> 16) & 1u)) >> 16;  // RNE
  return (uint16_t)r;
}
__device__ __forceinline__ float b2f(uint16_t u) {
  return __uint_as_float(((uint32_t)u) << 16);
}

// ---------------- cast / transpose helpers ----------------

__global__ __launch_bounds__(256) void cast_x_kernel(const float* __restrict__ x,
                                                     uint16_t* __restrict__ xb, int n4) {
  int i = blockIdx.x * 256 + threadIdx.x;
  if (i >= n4) return;
  f32x4 v = ((const f32x4*)x)[i];
  union { uint16_t u[4]; uint64_t q; } o;
  o.u[0] = f2b(v[0]); o.u[1] = f2b(v[1]); o.u[2] = f2b(v[2]); o.u[3] = f2b(v[3]);
  ((uint64_t*)xb)[i] = o.q;
}

// wt[n*K + k] = (bf16) w[k*N + n]
__global__ __launch_bounds__(256) void transpose_cast_kernel(const float* __restrict__ w,
                                                             uint16_t* __restrict__ wt,
                                                             int K, int N) {
  int i = blockIdx.x * 256 + threadIdx.x;
  if (i >= N * K) return;
  int n = i / K, k = i - n * K;
  wt[i] = f2b(w[(size_t)k * N + n]);
}

// ---------------- 128x128 GEMM: A via LDS ring-3 (24 KiB), B direct from L2 ------
// A [M][768] bf16 row-major; Bt [N][768] bf16 row-major (weights transposed).
// 256 threads / 4 waves (2M x 2N), wave tile 64x64, acc[4][4].
// A: ring-3 LDS, depth-2 prefetch, counted vmcnt(6) (= 4 B-loads + 2 A-stage newer
//    than A(t+1)'s pair) -- never drained mid-loop. Both-sides XOR swizzle (0 conflicts).
// B: per-wave global short8 fragment loads (16 rows x 64 B contiguous each, L2-hit),
//    depth-1 register double-buffer; compiler inserts the counted vmcnt before use.
// MODE 0: qkv epilogue (Q/K transposed via operand swap, V normal); MODE 1: proj f32.

template<int MODE>
__global__ __launch_bounds__(256, 3) void gemm_ring_kernel(
    const uint16_t* __restrict__ A, const uint16_t* __restrict__ Bt,
    const float* __restrict__ bias,
    uint16_t* __restrict__ Qb, uint16_t* __restrict__ Kb,
    uint16_t* __restrict__ Vb, float* __restrict__ outf) {
  constexpr int NT = 24;                       // 768 / 32
  constexpr int NB = (MODE == 0) ? 18 : 6;     // 128-col blocks
  constexpr int NWG = 256 * NB;                // 256 row-blocks of 128
  constexpr int CPX = NWG / 8;
  __shared__ uint16_t lds[3 * 4096];           // ring-3 of A[128][32] slots (8 KiB each)

  const int tid  = threadIdx.x;
  const int lane = tid & 63, w = tid >> 6;
  const int wm = w >> 1, wn = w & 1;
  const int lrow = lane & 15, kb = lane >> 4;

  int wg = (int)blockIdx.x;
  wg = (wg & 7) * CPX + (wg >> 3);             // bijective XCD swizzle (NWG%8==0)
  const int mblk = wg / NB, nblk = wg % NB;    // nblk fastest: A-panel L2 reuse
  const int m0 = mblk * 128, n0 = nblk * 128;
  const bool sw = (MODE == 0) && (n0 < 1536);  // Q/K blocks: swapped-operand MFMA

  // A staging: wave w covers rows [w*32,+32); lane l -> row (l>>2),
  // global 16B-chunk = (l&3)^((l>>3)&3) (inverse swizzle; linear LDS + swz read = id).
  const int grow  = lane >> 2;
  const int gslot = ((lane & 3) ^ ((lane >> 3) & 3)) << 3;
  const size_t arow0 = (size_t)(m0 + w * 32 + grow) * 768 + gslot;

  auto stage = [&](int ts, int sl) {
    const size_t ko = (size_t)ts * 32;
    uint16_t* la = lds + sl * 4096 + w * 1024;   // wave-uniform LDS dest
    gll16(A + arow0 + ko,            la);
    gll16(A + arow0 + ko + 16 * 768, la + 512);
  };

  // B fragment source rows (per-lane): row n0 + wn*64 + nf*16 + lrow, k-slice kb*8
  const uint16_t* brow = Bt + (size_t)(n0 + wn * 64 + lrow) * 768 + kb * 8;

  const int xslot = (kb ^ ((lrow >> 1) & 3)) << 3;  // swizzled read chunk (elements)

  f32x4 acc[4][4] = {};
  short8 bcur[4], bnxt[4];

  stage(0, 0); stage(1, 1);
#pragma unroll
  for (int nf = 0; nf < 4; ++nf)
    bcur[nf] = *(const short8*)(brow + (size_t)nf * 16 * 768);
  asm volatile("s_waitcnt vmcnt(0)" ::: "memory");
  __builtin_amdgcn_s_barrier();
  __builtin_amdgcn_sched_barrier(0);

  int sl = 0;
  for (int t = 0; t < NT; ++t) {
    if (t + 1 < NT) {
      const uint16_t* bsrc = brow + (size_t)(t + 1) * 32;
#pragma unroll
      for (int nf = 0; nf < 4; ++nf)
        bnxt[nf] = *(const short8*)(bsrc + (size_t)nf * 16 * 768);
    }
    const int sl2 = (sl >= 1) ? sl - 1 : 2;    // (t+2)%3
    if (t + 2 < NT) stage(t + 2, sl2);
    const uint16_t* sa = lds + sl * 4096;
    short8 av[4];
#pragma unroll
    for (int mf = 0; mf < 4; ++mf)
      av[mf] = *(const short8*)(sa + (wm * 64 + mf * 16 + lrow) * 32 + xslot);
    __builtin_amdgcn_s_setprio(1);
    if (sw) {
#pragma unroll
      for (int mf = 0; mf < 4; ++mf)
#pragma unroll
        for (int nf = 0; nf < 4; ++nf)
          acc[mf][nf] = __builtin_amdgcn_mfma_f32_16x16x32_bf16(bcur[nf], av[mf], acc[mf][nf], 0, 0, 0);
    } else {
#pragma unroll
      for (int mf = 0; mf < 4; ++mf)
#pragma unroll
        for (int nf = 0; nf < 4; ++nf)
          acc[mf][nf] = __builtin_amdgcn_mfma_f32_16x16x32_bf16(av[mf], bcur[nf], acc[mf][nf], 0, 0, 0);
    }
    __builtin_amdgcn_s_setprio(0);
    if (t < NT - 1) {
      if (t < NT - 2) asm volatile("s_waitcnt vmcnt(6)" ::: "memory");
      else            asm volatile("s_waitcnt vmcnt(4)" ::: "memory");
      __builtin_amdgcn_s_barrier();
      __builtin_amdgcn_sched_barrier(0);
    }
#pragma unroll
    for (int nf = 0; nf < 4; ++nf) bcur[nf] = bnxt[nf];
    sl = (sl == 2) ? 0 : sl + 1;
  }

  const float qscale = 0.015625f;  // 4096^-0.5
  if (MODE == 0) {
    const int which = n0 / 768;
    if (which < 2) {
      // swapped-operand MFMA -> frag col (lrow) = token, frag row (kb*4+r) = channel
      uint16_t* dst = (which == 0) ? Qb : Kb;
      const float sc = (which == 0) ? qscale : 1.0f;
#pragma unroll
      for (int mf = 0; mf < 4; ++mf) {
        const int token = m0 + wm * 64 + mf * 16 + lrow;
        const int b = token >> 12, nn = token & 4095;
#pragma unroll
        for (int nf = 0; nf < 4; ++nf) {
          const int colb = n0 + wn * 64 + nf * 16 + kb * 4;
#pragma unroll
          for (int r = 0; r < 4; ++r) {
            const int chan = colb + r - which * 768;
            const int g = chan / 48, d = chan - g * 48;
            dst[(((size_t)b * 16 + g) * 48 + d) * 4096 + nn] =
                f2b((acc[mf][nf][r] + bias[colb + r]) * sc);
          }
        }
      }
    } else {
#pragma unroll
      for (int mf = 0; mf < 4; ++mf) {
        const int rowb = m0 + wm * 64 + mf * 16 + kb * 4;
#pragma unroll
        for (int nf = 0; nf < 4; ++nf) {
          const int col = n0 + wn * 64 + nf * 16 + lrow;
          const int c = col - 1536, g = c / 48, d = c - g * 48;
          const float bb = bias[col];
#pragma unroll
          for (int r = 0; r < 4; ++r) {
            const int row = rowb + r;
            const int b = row >> 12, nn = row & 4095;
            Vb[(((size_t)b * 16 + g) * 4096 + nn) * 48 + d] = f2b(acc[mf][nf][r] + bb);
          }
        }
      }
    }
  } else {
#pragma unroll
    for (int mf = 0; mf < 4; ++mf) {
      const int rowb = m0 + wm * 64 + mf * 16 + kb * 4;
#pragma unroll
      for (int nf = 0; nf < 4; ++nf) {
        const int col = n0 + wn * 64 + nf * 16 + lrow;
        const float bb = bias[col];
#pragma unroll
        for (int r = 0; r < 4; ++r)
          outf[(size_t)(rowb + r) * 768 + col] = acc[mf][nf][r] + bb;
      }
    }
  }
}

// ---------------- logits via MFMA over token-K ----------------
// Qt,Kt: [bg][48][4096] bf16.  part[ch][bg][48][48] f32, ch in 0..7 (512 tokens each)

__global__ __launch_bounds__(256) void logits_mfma_kernel(
    const uint16_t* __restrict__ Qt, const uint16_t* __restrict__ Kt,
    float* __restrict__ part) {
  const int bg = blockIdx.x;     // 0..127
  const int ch = blockIdx.y;     // 0..7
  const int tid = threadIdx.x;
  const int lane = tid & 63, w = tid >> 6;
  const int lrow = lane & 15, kb = lane >> 4;

  const size_t qbase = (size_t)bg * 48 * 4096;
  const int tok0 = ch * 512 + w * 128;

  f32x4 acc[3][3] = {};
#pragma unroll
  for (int s = 0; s < 4; ++s) {
    const int tok = tok0 + s * 32 + kb * 8;
    short8 av[3], bvv[3];
#pragma unroll
    for (int dm = 0; dm < 3; ++dm) {
      av[dm]  = *(const short8*)(Qt + qbase + (size_t)(dm * 16 + lrow) * 4096 + tok);
      bvv[dm] = *(const short8*)(Kt + qbase + (size_t)(dm * 16 + lrow) * 4096 + tok);
    }
#pragma unroll
    for (int dm = 0; dm < 3; ++dm)
#pragma unroll
      for (int em = 0; em < 3; ++em)
        acc[dm][em] = __builtin_amdgcn_mfma_f32_16x16x32_bf16(av[dm], bvv[em], acc[dm][em], 0, 0, 0);
  }

  __shared__ float red[4][2304];
#pragma unroll
  for (int dm = 0; dm < 3; ++dm)
#pragma unroll
    for (int em = 0; em < 3; ++em)
#pragma unroll
      for (int r = 0; r < 4; ++r) {
        const int d = dm * 16 + kb * 4 + r;
        const int e = em * 16 + lrow;
        red[w][d * 48 + e] = acc[dm][em][r];
      }
  __syncthreads();
  float* dst = part + ((size_t)ch * 128 + bg) * 2304;
  for (int i = tid; i < 2304; i += 256)
    dst[i] = red[0][i] + red[1][i] + red[2][i] + red[3][i];
}

// ---------------- reduce partials + softmax over e ----------------

__global__ __launch_bounds__(256) void softmax_kernel(const float* __restrict__ part,
                                                      float* __restrict__ attn) {
  const int bg = blockIdx.x;
  const int tid = threadIdx.x;
  __shared__ float l[2304];
  for (int p = tid; p < 2304; p += 256) {
    float s = 0.f;
    for (int chk = 0; chk < 8; ++chk) s += part[((size_t)chk * 128 + bg) * 2304 + p];
    l[p] = s;
  }
  __syncthreads();
  if (tid < 48) {
    const int d = tid;
    float m = -1e30f;
    for (int e = 0; e < 48; ++e) m = fmaxf(m, l[d * 48 + e]);
    float s = 0.f;
    for (int e = 0; e < 48; ++e) s += expf(l[d * 48 + e] - m);
    const float inv = 1.0f / s;
    for (int e = 0; e < 48; ++e)
      attn[(size_t)bg * 2304 + d * 48 + e] = expf(l[d * 48 + e] - m) * inv;
  }
}

// ---------------- block-diag: ao[b][n][g*48+d] = sum_e attn[bg][d][e] * v[bg][n][e] ------

__global__ __launch_bounds__(256) void blockdiag_kernel(const uint16_t* __restrict__ Vb,
                                                        const float* __restrict__ attn,
                                                        uint16_t* __restrict__ ao) {
  const int bg = blockIdx.x, ch = blockIdx.y;
  const int b = bg >> 4, g = bg & 15;
  const int tid = threadIdx.x;
  __shared__ uint16_t vs[128 * 64];
  __shared__ uint16_t as2[48 * 64];
  const size_t vbase = ((size_t)bg * 4096 + (size_t)ch * 128) * 48;
  // vectorized V staging: 128 rows x 6 uint4-chunks (48 bf16 = 6 x 8)
  const uint4* vg = (const uint4*)(Vb + vbase);
  for (int u = tid; u < 768; u += 256) {
    const int n = u / 6, c = u - n * 6;
    *(uint4*)(vs + n * 64 + c * 8) = vg[u];
  }
  {  // zero the 16-col pad (cols 48..63), 128 rows x 2 chunks = 256 units
    const int n = tid >> 1, c = 6 + (tid & 1);
    uint4 z; z.x = z.y = z.z = z.w = 0u;
    *(uint4*)(vs + n * 64 + c * 8) = z;
  }
  const float* ab = attn + (size_t)bg * 2304;
  for (int i = tid; i < 48 * 64; i += 256) {
    int d = i >> 6, e = i & 63;
    as2[i] = (e < 48) ? f2b(ab[d * 48 + e]) : (uint16_t)0;
  }
  __syncthreads();
  const int lane = tid & 63, w = tid >> 6;
  const int lrow = lane & 15, kb = lane >> 4;
  f32x4 acc[2][3] = {};
#pragma unroll
  for (int ksb = 0; ksb < 2; ++ksb) {
    short8 a[2], bb[3];
#pragma unroll
    for (int i = 0; i < 2; ++i)
      a[i] = *(const short8*)(vs + (w * 32 + i * 16 + lrow) * 64 + ksb * 32 + kb * 8);
#pragma unroll
    for (int c = 0; c < 3; ++c)
      bb[c] = *(const short8*)(as2 + (c * 16 + lrow) * 64 + ksb * 32 + kb * 8);
#pragma unroll
    for (int i = 0; i < 2; ++i)
#pragma unroll
      for (int c = 0; c < 3; ++c)
        acc[i][c] = __builtin_amdgcn_mfma_f32_16x16x32_bf16(a[i], bb[c], acc[i][c], 0, 0, 0);
  }
#pragma unroll
  for (int i = 0; i < 2; ++i)
#pragma unroll
    for (int c = 0; c < 3; ++c)
#pragma unroll
      for (int r = 0; r < 4; ++r) {
        const int nl = w * 32 + i * 16 + kb * 4 + r;
        const int dcol = c * 16 + lrow;
        const size_t row = (size_t)b * 4096 + (size_t)ch * 128 + nl;
        ao[row * 768 + g * 48 + dcol] = f2b(acc[i][c][r]);
      }
}

// ---------------- launcher ----------------

extern "C" void kernel_launch(void* const* d_in, const int* in_sizes, int n_in,
                              void* d_out, int out_size, void* d_ws, size_t ws_size,
                              hipStream_t stream) {
  const float* x      = (const float*)d_in[0];
  const float* w_qkv  = (const float*)d_in[1];
  const float* b_qkv  = (const float*)d_in[2];
  const float* w_proj = (const float*)d_in[3];
  const float* b_proj = (const float*)d_in[4];
  float* out = (float*)d_out;

  char* w = (char*)d_ws;
  uint16_t* xb  = (uint16_t*)w; w += (size_t)32768 * 768 * 2;      // 50.3 MB (reused as ao)
  uint16_t* wqT = (uint16_t*)w; w += (size_t)2304 * 768 * 2;       // 3.5 MB
  uint16_t* wpT = (uint16_t*)w; w += (size_t)768 * 768 * 2;        // 1.2 MB
  uint16_t* Qt  = (uint16_t*)w; w += (size_t)128 * 48 * 4096 * 2;  // 50.3 MB
  uint16_t* Kt  = (uint16_t*)w; w += (size_t)128 * 48 * 4096 * 2;  // 50.3 MB
  uint16_t* Vb  = (uint16_t*)w; w += (size_t)128 * 4096 * 48 * 2;  // 50.3 MB
  float* part   = (float*)w;    w += (size_t)8 * 128 * 2304 * 4;   // 9.4 MB
  float* attn   = (float*)w;    w += (size_t)128 * 2304 * 4;       // 1.2 MB
  uint16_t* ao  = xb;  // x_bf16 is dead after gemm_qkv; alias to save workspace

  cast_x_kernel<<<24576, 256, 0, stream>>>(x, xb, 6291456);
  transpose_cast_kernel<<<6912, 256, 0, stream>>>(w_qkv, wqT, 768, 2304);
  transpose_cast_kernel<<<2304, 256, 0, stream>>>(w_proj, wpT, 768, 768);
  gemm_ring_kernel<0><<<4608, 256, 0, stream>>>(xb, wqT, b_qkv, Qt, Kt, Vb, nullptr);
  logits_mfma_kernel<<<dim3(128, 8), 256, 0, stream>>>(Qt, Kt, part);
  softmax_kernel<<<128, 256, 0, stream>>>(part, attn);
  blockdiag_kernel<<<dim3(128, 32), 256, 0, stream>>>(Vb, attn, ao);
  gemm_ring_kernel<1><<<1536, 256, 0, stream>>>(ao, wpT, b_proj, nullptr, nullptr, nullptr, out);
}

// Round 9
// 515.280 us; speedup vs baseline: 1.2855x; 1.2855x over previous
//
#include <hip/hip_runtime.h>
#include <stdint.h>

// Problem constants: B=8, N=4096, C=768, G=16, D=48
// qkv GEMM: M=32768, N=2304, K=768 ; proj GEMM: M=32768, N=768, K=768
//
// Toolchain law (rounds 3-8, six data points): ANY __launch_bounds__ second arg
// >= 2 crushes the per-wave VGPR budget ((512,1)->128, (256,2)->96, (256,3)->84)
// and spills the accumulator to scratch (seen as GB-scale WRITE_SIZE). A bare
// __launch_bounds__(256) allocates freely (136/236 observed, zero spill).
// So: 256-thread blocks, no min-waves arg, keep natural VGPR ~<=170.

using short8 = __attribute__((__ext_vector_type__(8))) short;
using f32x4  = __attribute__((__ext_vector_type__(4))) float;

typedef const void __attribute__((address_space(1))) gv_t;
typedef void __attribute__((address_space(3))) lv_t;

__device__ __forceinline__ void gll16(const void* g, void* l) {
  __builtin_amdgcn_global_load_lds((gv_t*)g, (lv_t*)l, 16, 0, 0);
}

__device__ __forceinline__ uint16_t f2b(float f) {
  uint32_t x = __float_as_uint(f);
  uint32_t r = (x + 0x7fffu + ((x >> 16) & 1u)) >> 16;  // RNE
  return (uint16_t)r;
}
__device__ __forceinline__ float b2f(uint16_t u) {
  return __uint_as_float(((uint32_t)u) << 16);
}

// ---------------- cast / transpose helpers ----------------

__global__ __launch_bounds__(256) void cast_x_kernel(const float* __restrict__ x,
                                                     uint16_t* __restrict__ xb, int n4) {
  int i = blockIdx.x * 256 + threadIdx.x;
  if (i >= n4) return;
  f32x4 v = ((const f32x4*)x)[i];
  union { uint16_t u[4]; uint64_t q; } o;
  o.u[0] = f2b(v[0]); o.u[1] = f2b(v[1]); o.u[2] = f2b(v[2]); o.u[3] = f2b(v[3]);
  ((uint64_t*)xb)[i] = o.q;
}

// wt[n*K + k] = (bf16) w[k*N + n]
__global__ __launch_bounds__(256) void transpose_cast_kernel(const float* __restrict__ w,
                                                             uint16_t* __restrict__ wt,
                                                             int K, int N) {
  int i = blockIdx.x * 256 + threadIdx.x;
  if (i >= N * K) return;
  int n = i / K, k = i - n * K;
  wt[i] = f2b(w[(size_t)k * N + n]);
}

// ---------------- 128x128 GEMM: A via LDS ring-3 (24 KiB), B direct from L2 ------
// A [M][768] bf16 row-major; Bt [N][768] bf16 row-major (weights transposed).
// 256 threads / 4 waves (2M x 2N), wave tile 64x64, acc[4][4].
// A: ring-3 LDS, depth-2 prefetch, counted vmcnt(6) (= 4 B-loads + 2 A-stage newer
//    than A(t+1)'s pair) -- never drained mid-loop. Both-sides XOR swizzle (0 conflicts).
// B: per-wave global short8 fragment loads (16 rows x 64 B contiguous each, L2-hit),
//    depth-1 register double-buffer; compiler inserts the counted vmcnt before use.
// MODE 0: qkv epilogue (Q/K transposed via operand swap, V normal); MODE 1: proj f32.

template<int MODE>
__global__ __launch_bounds__(256) void gemm_ring_kernel(
    const uint16_t* __restrict__ A, const uint16_t* __restrict__ Bt,
    const float* __restrict__ bias,
    uint16_t* __restrict__ Qb, uint16_t* __restrict__ Kb,
    uint16_t* __restrict__ Vb, float* __restrict__ outf) {
  constexpr int NT = 24;                       // 768 / 32
  constexpr int NB = (MODE == 0) ? 18 : 6;     // 128-col blocks
  constexpr int NWG = 256 * NB;                // 256 row-blocks of 128
  constexpr int CPX = NWG / 8;
  __shared__ uint16_t lds[3 * 4096];           // ring-3 of A[128][32] slots (8 KiB each)

  const int tid  = threadIdx.x;
  const int lane = tid & 63, w = tid >> 6;
  const int wm = w >> 1, wn = w & 1;
  const int lrow = lane & 15, kb = lane >> 4;

  int wg = (int)blockIdx.x;
  wg = (wg & 7) * CPX + (wg >> 3);             // bijective XCD swizzle (NWG%8==0)
  const int mblk = wg / NB, nblk = wg % NB;    // nblk fastest: A-panel L2 reuse
  const int m0 = mblk * 128, n0 = nblk * 128;
  const bool sw = (MODE == 0) && (n0 < 1536);  // Q/K blocks: swapped-operand MFMA

  // A staging: wave w covers rows [w*32,+32); lane l -> row (l>>2),
  // global 16B-chunk = (l&3)^((l>>3)&3) (inverse swizzle; linear LDS + swz read = id).
  const int grow  = lane >> 2;
  const int gslot = ((lane & 3) ^ ((lane >> 3) & 3)) << 3;
  const size_t arow0 = (size_t)(m0 + w * 32 + grow) * 768 + gslot;

  auto stage = [&](int ts, int sl) {
    const size_t ko = (size_t)ts * 32;
    uint16_t* la = lds + sl * 4096 + w * 1024;   // wave-uniform LDS dest
    gll16(A + arow0 + ko,            la);
    gll16(A + arow0 + ko + 16 * 768, la + 512);
  };

  // B fragment source rows (per-lane): row n0 + wn*64 + nf*16 + lrow, k-slice kb*8
  const uint16_t* brow = Bt + (size_t)(n0 + wn * 64 + lrow) * 768 + kb * 8;

  const int xslot = (kb ^ ((lrow >> 1) & 3)) << 3;  // swizzled read chunk (elements)

  f32x4 acc[4][4] = {};
  short8 bcur[4], bnxt[4];

  stage(0, 0); stage(1, 1);
#pragma unroll
  for (int nf = 0; nf < 4; ++nf)
    bcur[nf] = *(const short8*)(brow + (size_t)nf * 16 * 768);
  asm volatile("s_waitcnt vmcnt(0)" ::: "memory");
  __builtin_amdgcn_s_barrier();
  __builtin_amdgcn_sched_barrier(0);

  int sl = 0;
  for (int t = 0; t < NT; ++t) {
    if (t + 1 < NT) {
      const uint16_t* bsrc = brow + (size_t)(t + 1) * 32;
#pragma unroll
      for (int nf = 0; nf < 4; ++nf)
        bnxt[nf] = *(const short8*)(bsrc + (size_t)nf * 16 * 768);
    }
    const int sl2 = (sl >= 1) ? sl - 1 : 2;    // (t+2)%3
    if (t + 2 < NT) stage(t + 2, sl2);
    const uint16_t* sa = lds + sl * 4096;
    short8 av[4];
#pragma unroll
    for (int mf = 0; mf < 4; ++mf)
      av[mf] = *(const short8*)(sa + (wm * 64 + mf * 16 + lrow) * 32 + xslot);
    __builtin_amdgcn_s_setprio(1);
    if (sw) {
#pragma unroll
      for (int mf = 0; mf < 4; ++mf)
#pragma unroll
        for (int nf = 0; nf < 4; ++nf)
          acc[mf][nf] = __builtin_amdgcn_mfma_f32_16x16x32_bf16(bcur[nf], av[mf], acc[mf][nf], 0, 0, 0);
    } else {
#pragma unroll
      for (int mf = 0; mf < 4; ++mf)
#pragma unroll
        for (int nf = 0; nf < 4; ++nf)
          acc[mf][nf] = __builtin_amdgcn_mfma_f32_16x16x32_bf16(av[mf], bcur[nf], acc[mf][nf], 0, 0, 0);
    }
    __builtin_amdgcn_s_setprio(0);
    if (t < NT - 1) {
      if (t < NT - 2) asm volatile("s_waitcnt vmcnt(6)" ::: "memory");
      else            asm volatile("s_waitcnt vmcnt(4)" ::: "memory");
      __builtin_amdgcn_s_barrier();
      __builtin_amdgcn_sched_barrier(0);
    }
#pragma unroll
    for (int nf = 0; nf < 4; ++nf) bcur[nf] = bnxt[nf];
    sl = (sl == 2) ? 0 : sl + 1;
  }

  const float qscale = 0.015625f;  // 4096^-0.5
  if (MODE == 0) {
    const int which = n0 / 768;
    if (which < 2) {
      // swapped-operand MFMA -> frag col (lrow) = token, frag row (kb*4+r) = channel
      uint16_t* dst = (which == 0) ? Qb : Kb;
      const float sc = (which == 0) ? qscale : 1.0f;
#pragma unroll
      for (int mf = 0; mf < 4; ++mf) {
        const int token = m0 + wm * 64 + mf * 16 + lrow;
        const int b = token >> 12, nn = token & 4095;
#pragma unroll
        for (int nf = 0; nf < 4; ++nf) {
          const int colb = n0 + wn * 64 + nf * 16 + kb * 4;
#pragma unroll
          for (int r = 0; r < 4; ++r) {
            const int chan = colb + r - which * 768;
            const int g = chan / 48, d = chan - g * 48;
            dst[(((size_t)b * 16 + g) * 48 + d) * 4096 + nn] =
                f2b((acc[mf][nf][r] + bias[colb + r]) * sc);
          }
        }
      }
    } else {
#pragma unroll
      for (int mf = 0; mf < 4; ++mf) {
        const int rowb = m0 + wm * 64 + mf * 16 + kb * 4;
#pragma unroll
        for (int nf = 0; nf < 4; ++nf) {
          const int col = n0 + wn * 64 + nf * 16 + lrow;
          const int c = col - 1536, g = c / 48, d = c - g * 48;
          const float bb = bias[col];
#pragma unroll
          for (int r = 0; r < 4; ++r) {
            const int row = rowb + r;
            const int b = row >> 12, nn = row & 4095;
            Vb[(((size_t)b * 16 + g) * 4096 + nn) * 48 + d] = f2b(acc[mf][nf][r] + bb);
          }
        }
      }
    }
  } else {
#pragma unroll
    for (int mf = 0; mf < 4; ++mf) {
      const int rowb = m0 + wm * 64 + mf * 16 + kb * 4;
#pragma unroll
      for (int nf = 0; nf < 4; ++nf) {
        const int col = n0 + wn * 64 + nf * 16 + lrow;
        const float bb = bias[col];
#pragma unroll
        for (int r = 0; r < 4; ++r)
          outf[(size_t)(rowb + r) * 768 + col] = acc[mf][nf][r] + bb;
      }
    }
  }
}

// ---------------- logits via MFMA over token-K ----------------
// Qt,Kt: [bg][48][4096] bf16.  part[ch][bg][48][48] f32, ch in 0..7 (512 tokens each)

__global__ __launch_bounds__(256) void logits_mfma_kernel(
    const uint16_t* __restrict__ Qt, const uint16_t* __restrict__ Kt,
    float* __restrict__ part) {
  const int bg = blockIdx.x;     // 0..127
  const int ch = blockIdx.y;     // 0..7
  const int tid = threadIdx.x;
  const int lane = tid & 63, w = tid >> 6;
  const int lrow = lane & 15, kb = lane >> 4;

  const size_t qbase = (size_t)bg * 48 * 4096;
  const int tok0 = ch * 512 + w * 128;

  f32x4 acc[3][3] = {};
#pragma unroll
  for (int s = 0; s < 4; ++s) {
    const int tok = tok0 + s * 32 + kb * 8;
    short8 av[3], bvv[3];
#pragma unroll
    for (int dm = 0; dm < 3; ++dm) {
      av[dm]  = *(const short8*)(Qt + qbase + (size_t)(dm * 16 + lrow) * 4096 + tok);
      bvv[dm] = *(const short8*)(Kt + qbase + (size_t)(dm * 16 + lrow) * 4096 + tok);
    }
#pragma unroll
    for (int dm = 0; dm < 3; ++dm)
#pragma unroll
      for (int em = 0; em < 3; ++em)
        acc[dm][em] = __builtin_amdgcn_mfma_f32_16x16x32_bf16(av[dm], bvv[em], acc[dm][em], 0, 0, 0);
  }

  __shared__ float red[4][2304];
#pragma unroll
  for (int dm = 0; dm < 3; ++dm)
#pragma unroll
    for (int em = 0; em < 3; ++em)
#pragma unroll
      for (int r = 0; r < 4; ++r) {
        const int d = dm * 16 + kb * 4 + r;
        const int e = em * 16 + lrow;
        red[w][d * 48 + e] = acc[dm][em][r];
      }
  __syncthreads();
  float* dst = part + ((size_t)ch * 128 + bg) * 2304;
  for (int i = tid; i < 2304; i += 256)
    dst[i] = red[0][i] + red[1][i] + red[2][i] + red[3][i];
}

// ---------------- reduce partials + softmax over e ----------------

__global__ __launch_bounds__(256) void softmax_kernel(const float* __restrict__ part,
                                                      float* __restrict__ attn) {
  const int bg = blockIdx.x;
  const int tid = threadIdx.x;
  __shared__ float l[2304];
  for (int p = tid; p < 2304; p += 256) {
    float s = 0.f;
    for (int chk = 0; chk < 8; ++chk) s += part[((size_t)chk * 128 + bg) * 2304 + p];
    l[p] = s;
  }
  __syncthreads();
  if (tid < 48) {
    const int d = tid;
    float m = -1e30f;
    for (int e = 0; e < 48; ++e) m = fmaxf(m, l[d * 48 + e]);
    float s = 0.f;
    for (int e = 0; e < 48; ++e) s += expf(l[d * 48 + e] - m);
    const float inv = 1.0f / s;
    for (int e = 0; e < 48; ++e)
      attn[(size_t)bg * 2304 + d * 48 + e] = expf(l[d * 48 + e] - m) * inv;
  }
}

// ---------------- block-diag: ao[b][n][g*48+d] = sum_e attn[bg][d][e] * v[bg][n][e] ------

__global__ __launch_bounds__(256) void blockdiag_kernel(const uint16_t* __restrict__ Vb,
                                                        const float* __restrict__ attn,
                                                        uint16_t* __restrict__ ao) {
  const int bg = blockIdx.x, ch = blockIdx.y;
  const int b = bg >> 4, g = bg & 15;
  const int tid = threadIdx.x;
  __shared__ uint16_t vs[128 * 64];
  __shared__ uint16_t as2[48 * 64];
  const size_t vbase = ((size_t)bg * 4096 + (size_t)ch * 128) * 48;
  // vectorized V staging: 128 rows x 6 uint4-chunks (48 bf16 = 6 x 8)
  const uint4* vg = (const uint4*)(Vb + vbase);
  for (int u = tid; u < 768; u += 256) {
    const int n = u / 6, c = u - n * 6;
    *(uint4*)(vs + n * 64 + c * 8) = vg[u];
  }
  {  // zero the 16-col pad (cols 48..63), 128 rows x 2 chunks = 256 units
    const int n = tid >> 1, c = 6 + (tid & 1);
    uint4 z; z.x = z.y = z.z = z.w = 0u;
    *(uint4*)(vs + n * 64 + c * 8) = z;
  }
  const float* ab = attn + (size_t)bg * 2304;
  for (int i = tid; i < 48 * 64; i += 256) {
    int d = i >> 6, e = i & 63;
    as2[i] = (e < 48) ? f2b(ab[d * 48 + e]) : (uint16_t)0;
  }
  __syncthreads();
  const int lane = tid & 63, w = tid >> 6;
  const int lrow = lane & 15, kb = lane >> 4;
  f32x4 acc[2][3] = {};
#pragma unroll
  for (int ksb = 0; ksb < 2; ++ksb) {
    short8 a[2], bb[3];
#pragma unroll
    for (int i = 0; i < 2; ++i)
      a[i] = *(const short8*)(vs + (w * 32 + i * 16 + lrow) * 64 + ksb * 32 + kb * 8);
#pragma unroll
    for (int c = 0; c < 3; ++c)
      bb[c] = *(const short8*)(as2 + (c * 16 + lrow) * 64 + ksb * 32 + kb * 8);
#pragma unroll
    for (int i = 0; i < 2; ++i)
#pragma unroll
      for (int c = 0; c < 3; ++c)
        acc[i][c] = __builtin_amdgcn_mfma_f32_16x16x32_bf16(a[i], bb[c], acc[i][c], 0, 0, 0);
  }
#pragma unroll
  for (int i = 0; i < 2; ++i)
#pragma unroll
    for (int c = 0; c < 3; ++c)
#pragma unroll
      for (int r = 0; r < 4; ++r) {
        const int nl = w * 32 + i * 16 + kb * 4 + r;
        const int dcol = c * 16 + lrow;
        const size_t row = (size_t)b * 4096 + (size_t)ch * 128 + nl;
        ao[row * 768 + g * 48 + dcol] = f2b(acc[i][c][r]);
      }
}

// ---------------- launcher ----------------

extern "C" void kernel_launch(void* const* d_in, const int* in_sizes, int n_in,
                              void* d_out, int out_size, void* d_ws, size_t ws_size,
                              hipStream_t stream) {
  const float* x      = (const float*)d_in[0];
  const float* w_qkv  = (const float*)d_in[1];
  const float* b_qkv  = (const float*)d_in[2];
  const float* w_proj = (const float*)d_in[3];
  const float* b_proj = (const float*)d_in[4];
  float* out = (float*)d_out;

  char* w = (char*)d_ws;
  uint16_t* xb  = (uint16_t*)w; w += (size_t)32768 * 768 * 2;      // 50.3 MB (reused as ao)
  uint16_t* wqT = (uint16_t*)w; w += (size_t)2304 * 768 * 2;       // 3.5 MB
  uint16_t* wpT = (uint16_t*)w; w += (size_t)768 * 768 * 2;        // 1.2 MB
  uint16_t* Qt  = (uint16_t*)w; w += (size_t)128 * 48 * 4096 * 2;  // 50.3 MB
  uint16_t* Kt  = (uint16_t*)w; w += (size_t)128 * 48 * 4096 * 2;  // 50.3 MB
  uint16_t* Vb  = (uint16_t*)w; w += (size_t)128 * 4096 * 48 * 2;  // 50.3 MB
  float* part   = (float*)w;    w += (size_t)8 * 128 * 2304 * 4;   // 9.4 MB
  float* attn   = (float*)w;    w += (size_t)128 * 2304 * 4;       // 1.2 MB
  uint16_t* ao  = xb;  // x_bf16 is dead after gemm_qkv; alias to save workspace

  cast_x_kernel<<<24576, 256, 0, stream>>>(x, xb, 6291456);
  transpose_cast_kernel<<<6912, 256, 0, stream>>>(w_qkv, wqT, 768, 2304);
  transpose_cast_kernel<<<2304, 256, 0, stream>>>(w_proj, wpT, 768, 768);
  gemm_ring_kernel<0><<<4608, 256, 0, stream>>>(xb, wqT, b_qkv, Qt, Kt, Vb, nullptr);
  logits_mfma_kernel<<<dim3(128, 8), 256, 0, stream>>>(Qt, Kt, part);
  softmax_kernel<<<128, 256, 0, stream>>>(part, attn);
  blockdiag_kernel<<<dim3(128, 32), 256, 0, stream>>>(Vb, attn, ao);
  gemm_ring_kernel<1><<<1536, 256, 0, stream>>>(ao, wpT, b_proj, nullptr, nullptr, nullptr, out);
}

// Round 10
// 400.945 us; speedup vs baseline: 1.6521x; 1.2852x over previous
//
#include <hip/hip_runtime.h>
#include <stdint.h>

// Problem: B=8, N=4096, C=768, G=16, D=48
// Algebraic restructure (R10): attn logits L_bg = Wq_g^T (X^T X) Wk_g (+ bias rank-1
// terms). So we never compute Q/K: V-only GEMM (M=32768,N=768,K=768), Gram G_b = X^T X
// per batch (768x768, K=4096), Tt_b = WkT @ G_b, L = wq_row . Tt_row (+softmax, fused).
// All GEMMs use the round-2-verified 2-phase 128x128 core (202us-class) verbatim.
// Toolchain law (R3-R9): 512-thr blocks VGPR-cap at 128 (spill); launch_bounds 2nd
// arg >=2 crushes VGPR; hand vmcnt/sched_barrier pipelines lose to compiler. So:
// bare __launch_bounds__(256), plain __syncthreads 2-phase, compiler-scheduled.

using short8 = __attribute__((__ext_vector_type__(8))) short;
using f32x4  = __attribute__((__ext_vector_type__(4))) float;

typedef const void __attribute__((address_space(1))) gv_t;
typedef void __attribute__((address_space(3))) lv_t;

__device__ __forceinline__ void gll16(const void* g, void* l) {
  __builtin_amdgcn_global_load_lds((gv_t*)g, (lv_t*)l, 16, 0, 0);
}

__device__ __forceinline__ uint16_t f2b(float f) {
  uint32_t x = __float_as_uint(f);
  uint32_t r = (x + 0x7fffu + ((x >> 16) & 1u)) >> 16;  // RNE
  return (uint16_t)r;
}
__device__ __forceinline__ float b2f(uint16_t u) {
  return __uint_as_float(((uint32_t)u) << 16);
}

// ---------------- cast x -> xb (row-major bf16) + xt (channel-major bf16) ----------

__global__ __launch_bounds__(256) void cast_xt_kernel(const float* __restrict__ x,
                                                      uint16_t* __restrict__ xb,
                                                      uint16_t* __restrict__ xt) {
  __shared__ uint16_t lt[64 * 65];             // pad 65: conflict-free transpose
  const int b  = blockIdx.y;
  const int tn = blockIdx.x & 63, tp = blockIdx.x >> 6;   // 64 n-tiles x 12 p-tiles
  const int n0 = tn * 64, p0 = tp * 64;
  const int tid = threadIdx.x;
  const int r = tid >> 2, cs = (tid & 3) << 4;

  // phase 1: read 64x64 f32 tile, write xb, stage bf16 in LDS
  const size_t xrow = ((size_t)(b * 4096 + n0 + r)) * 768 + p0 + cs;
  uint16_t v[16];
#pragma unroll
  for (int j = 0; j < 4; ++j) {
    f32x4 f = *(const f32x4*)(x + xrow + 4 * j);
#pragma unroll
    for (int k = 0; k < 4; ++k) v[4 * j + k] = f2b(f[k]);
  }
  *(uint4*)(xb + xrow)     = *(const uint4*)&v[0];
  *(uint4*)(xb + xrow + 8) = *(const uint4*)&v[8];
#pragma unroll
  for (int j = 0; j < 16; ++j) lt[r * 65 + cs + j] = v[j];
  __syncthreads();

  // phase 2: write transposed tile to xt[b][p][n]
  const int pr = tid >> 2, ns = (tid & 3) << 4;
  uint16_t o[16];
#pragma unroll
  for (int j = 0; j < 16; ++j) o[j] = lt[(ns + j) * 65 + pr];
  const size_t trow = ((size_t)(b * 768 + p0 + pr)) * 4096 + n0 + ns;
  *(uint4*)(xt + trow)     = *(const uint4*)&o[0];
  *(uint4*)(xt + trow + 8) = *(const uint4*)&o[8];
}

// wt[n*K + k] = (bf16) w[k*N + n]
__global__ __launch_bounds__(256) void transpose_cast_kernel(const float* __restrict__ w,
                                                             uint16_t* __restrict__ wt,
                                                             int K, int N) {
  int i = blockIdx.x * 256 + threadIdx.x;
  if (i >= N * K) return;
  int n = i / K, k = i - n * K;
  wt[i] = f2b(w[(size_t)k * N + n]);
}

// ---------------- R2-verified 2-phase 128x128 GEMM core ----------------
// C[m][n] = sum_k A[m0+m][k] * Bt[n0+n][k]; 4 waves (2x2), wave tile 64x64, acc[4][4].

template<int NT>
__device__ __forceinline__ void gemm2p_core(
    const uint16_t* __restrict__ A, int lda,
    const uint16_t* __restrict__ Bt, int ldb,
    int m0, int n0, int tid, uint16_t* As, uint16_t* Bs, f32x4 (&acc)[4][4]) {
  const int lane = tid & 63, wid = tid >> 6;
  const int wr = wid >> 1, wc = wid & 1;
  const int lrow = lane & 15, kb = lane >> 4;
  const int off  = tid * 16;
  const int srow = off >> 6;
  const int scol = (off & 63) >> 1;

  for (int t = 0; t < NT; ++t) {
    const int k0 = t * 32;
    gll16(A  + (size_t)(m0 + srow)      * lda + k0 + scol, (char*)As + off);
    gll16(A  + (size_t)(m0 + 64 + srow) * lda + k0 + scol, (char*)As + 4096 + off);
    gll16(Bt + (size_t)(n0 + srow)      * ldb + k0 + scol, (char*)Bs + off);
    gll16(Bt + (size_t)(n0 + 64 + srow) * ldb + k0 + scol, (char*)Bs + 4096 + off);
    __syncthreads();
    short8 av[4], bv[4];
#pragma unroll
    for (int m = 0; m < 4; ++m)
      av[m] = *(const short8*)(As + (wr * 64 + m * 16 + lrow) * 32 + kb * 8);
#pragma unroll
    for (int n = 0; n < 4; ++n)
      bv[n] = *(const short8*)(Bs + (wc * 64 + n * 16 + lrow) * 32 + kb * 8);
#pragma unroll
    for (int m = 0; m < 4; ++m)
#pragma unroll
      for (int n = 0; n < 4; ++n)
        acc[m][n] = __builtin_amdgcn_mfma_f32_16x16x32_bf16(av[m], bv[n], acc[m][n], 0, 0, 0);
    __syncthreads();
  }
}

__device__ __forceinline__ int xcd_swizzle(int wg, int cpx) {
  return (wg & 7) * cpx + (wg >> 3);
}

// ---- V GEMM: A=xb[32768][768], Bt=wvT[768][768], out Vb [bg][n][48] bf16 + bias ----

__global__ __launch_bounds__(256) void vgemm_kernel(
    const uint16_t* __restrict__ A, const uint16_t* __restrict__ Bt,
    const float* __restrict__ bias, uint16_t* __restrict__ Vb) {
  __shared__ uint16_t As[128 * 32];
  __shared__ uint16_t Bs[128 * 32];
  const int tid = threadIdx.x;
  int wg = xcd_swizzle((int)blockIdx.x, 1536 / 8);
  const int mblk = wg / 6, nblk = wg % 6;      // nblk fastest: A-panel L2 reuse
  const int m0 = mblk * 128, n0 = nblk * 128;

  f32x4 acc[4][4] = {};
  gemm2p_core<24>(A, 768, Bt, 768, m0, n0, tid, As, Bs, acc);

  const int lane = tid & 63, wid = tid >> 6;
  const int wr = wid >> 1, wc = wid & 1;
  const int lrow = lane & 15, kb = lane >> 4;
#pragma unroll
  for (int mf = 0; mf < 4; ++mf) {
    const int rowb = m0 + wr * 64 + mf * 16 + kb * 4;
#pragma unroll
    for (int nf = 0; nf < 4; ++nf) {
      const int c = n0 + wc * 64 + nf * 16 + lrow;   // 0..767 within V
      const int g = c / 48, d = c - g * 48;
      const float bb = bias[1536 + c];
#pragma unroll
      for (int r = 0; r < 4; ++r) {
        const int row = rowb + r;
        const int b = row >> 12, nn = row & 4095;
        Vb[(((size_t)b * 16 + g) * 4096 + nn) * 48 + d] = f2b(acc[mf][nf][r] + bb);
      }
    }
  }
}

// ---- Gram: G2[ks][b][p][q] = sum_{n in half ks} xt[b][p][n] xt[b][q][n], f32 ----

__global__ __launch_bounds__(256) void gram_kernel(const uint16_t* __restrict__ xt,
                                                   float* __restrict__ G2) {
  __shared__ uint16_t As[128 * 32];
  __shared__ uint16_t Bs[128 * 32];
  const int tid = threadIdx.x;
  int wg = xcd_swizzle((int)blockIdx.x, 576 / 8);
  const int b = wg / 72;
  const int rem = wg % 72;
  const int ks = rem / 36;
  const int rr = rem % 36;
  const int m0 = (rr / 6) * 128, n0 = (rr % 6) * 128;

  const uint16_t* xtb = xt + (size_t)b * 768 * 4096 + (size_t)ks * 2048;
  f32x4 acc[4][4] = {};
  gemm2p_core<64>(xtb, 4096, xtb, 4096, m0, n0, tid, As, Bs, acc);

  float* out = G2 + ((size_t)ks * 8 + b) * 589824;
  const int lane = tid & 63, wid = tid >> 6;
  const int wr = wid >> 1, wc = wid & 1;
  const int lrow = lane & 15, kb = lane >> 4;
#pragma unroll
  for (int mf = 0; mf < 4; ++mf) {
    const int rowb = m0 + wr * 64 + mf * 16 + kb * 4;
#pragma unroll
    for (int nf = 0; nf < 4; ++nf) {
      const int col = n0 + wc * 64 + nf * 16 + lrow;
#pragma unroll
      for (int r = 0; r < 4; ++r)
        out[(size_t)(rowb + r) * 768 + col] = acc[mf][nf][r];
    }
  }
}

__global__ __launch_bounds__(256) void reduceg_kernel(const float* __restrict__ G2,
                                                      uint16_t* __restrict__ G) {
  const size_t i = ((size_t)blockIdx.x * 256 + threadIdx.x) * 4;
  f32x4 a = *(const f32x4*)(G2 + i);
  f32x4 c = *(const f32x4*)(G2 + 4718592 + i);
  uint16_t o[4];
#pragma unroll
  for (int j = 0; j < 4; ++j) o[j] = f2b(a[j] + c[j]);
  *(uint64_t*)(G + i) = *(const uint64_t*)&o[0];
}

// ---- Tt GEMM: Tt_b[c'][p] = sum_q wkT[c'][q] G_b[p][q]  (G symmetric), bf16 out ----

__global__ __launch_bounds__(256) void ttgemm_kernel(const uint16_t* __restrict__ wkT,
                                                     const uint16_t* __restrict__ G,
                                                     uint16_t* __restrict__ Tt) {
  __shared__ uint16_t As[128 * 32];
  __shared__ uint16_t Bs[128 * 32];
  const int tid = threadIdx.x;
  int wg = xcd_swizzle((int)blockIdx.x, 288 / 8);
  const int b = wg / 36;
  const int rr = wg % 36;
  const int m0 = (rr / 6) * 128, n0 = (rr % 6) * 128;

  const uint16_t* Gb = G + (size_t)b * 589824;
  f32x4 acc[4][4] = {};
  gemm2p_core<24>(wkT, 768, Gb, 768, m0, n0, tid, As, Bs, acc);

  uint16_t* out = Tt + (size_t)b * 589824;
  const int lane = tid & 63, wid = tid >> 6;
  const int wr = wid >> 1, wc = wid & 1;
  const int lrow = lane & 15, kb = lane >> 4;
#pragma unroll
  for (int mf = 0; mf < 4; ++mf) {
    const int rowb = m0 + wr * 64 + mf * 16 + kb * 4;
#pragma unroll
    for (int nf = 0; nf < 4; ++nf) {
      const int col = n0 + wc * 64 + nf * 16 + lrow;
#pragma unroll
      for (int r = 0; r < 4; ++r)
        out[(size_t)(rowb + r) * 768 + col] = f2b(acc[mf][nf][r]);
    }
  }
}

// ---- s[b][p] = sum_n xt[b][p][n] ----

__global__ __launch_bounds__(256) void sb_kernel(const uint16_t* __restrict__ xt,
                                                 float* __restrict__ s) {
  const int j = blockIdx.x * 256 + threadIdx.x;   // 0..6143
  const uint16_t* row = xt + (size_t)j * 4096;
  float acc = 0.f;
  for (int i = 0; i < 4096; i += 8) {
    short8 v = *(const short8*)(row + i);
#pragma unroll
    for (int k = 0; k < 8; ++k) acc += b2f((uint16_t)v[k]);
  }
  s[j] = acc;
}

// ---- swv[b][c] = sum_p s[b][p] wT[c][p], c in 0..1535 (Q then K weight cols) ----

__global__ __launch_bounds__(256) void sw_kernel(const float* __restrict__ s,
                                                 const uint16_t* __restrict__ wqT,
                                                 float* __restrict__ swv) {
  __shared__ float sl[768];
  const int b = blockIdx.x / 6, cblk = blockIdx.x % 6;
  const int tid = threadIdx.x;
  for (int i = tid; i < 768; i += 256) sl[i] = s[b * 768 + i];
  __syncthreads();
  const int c = cblk * 256 + tid;
  const uint16_t* wr = wqT + (size_t)c * 768;
  float acc = 0.f;
  for (int p = 0; p < 768; p += 8) {
    short8 v = *(const short8*)(wr + p);
#pragma unroll
    for (int k = 0; k < 8; ++k) acc += sl[p + k] * b2f((uint16_t)v[k]);
  }
  swv[b * 1536 + c] = acc;
}

// ---- logits48: L_bg[d][e] = sum_p wqT[g*48+d][p] Tt_b[g*48+e][p] (+bias) -> softmax ----

__global__ __launch_bounds__(256) void logits48_kernel(
    const uint16_t* __restrict__ wqT, const uint16_t* __restrict__ Tt,
    const float* __restrict__ swv, const float* __restrict__ bqkv,
    float* __restrict__ attn) {
  const int bg = blockIdx.x;                 // 0..127
  const int b = bg >> 4, g = bg & 15;
  const int tid = threadIdx.x;
  const int lane = tid & 63, w = tid >> 6;
  const int lrow = lane & 15, kb = lane >> 4;

  const uint16_t* ttb = Tt + (size_t)b * 589824;
  f32x4 acc[3][3] = {};
#pragma unroll
  for (int s = 0; s < 6; ++s) {
    const int p = w * 192 + s * 32 + kb * 8;
    short8 av[3], bv[3];
#pragma unroll
    for (int dm = 0; dm < 3; ++dm) {
      av[dm] = *(const short8*)(wqT + (size_t)(g * 48 + dm * 16 + lrow) * 768 + p);
      bv[dm] = *(const short8*)(ttb + (size_t)(g * 48 + dm * 16 + lrow) * 768 + p);
    }
#pragma unroll
    for (int dm = 0; dm < 3; ++dm)
#pragma unroll
      for (int em = 0; em < 3; ++em)
        acc[dm][em] = __builtin_amdgcn_mfma_f32_16x16x32_bf16(av[dm], bv[em], acc[dm][em], 0, 0, 0);
  }

  __shared__ float red[4][2304];
#pragma unroll
  for (int dm = 0; dm < 3; ++dm)
#pragma unroll
    for (int em = 0; em < 3; ++em)
#pragma unroll
      for (int r = 0; r < 4; ++r) {
        const int d = dm * 16 + kb * 4 + r;
        const int e = em * 16 + lrow;
        red[w][d * 48 + e] = acc[dm][em][r];
      }
  __syncthreads();
  for (int i = tid; i < 2304; i += 256) {
    float v = red[0][i] + red[1][i] + red[2][i] + red[3][i];
    const int d = i / 48, e = i - d * 48;
    const float bq = bqkv[g * 48 + d];
    const float bk = bqkv[768 + g * 48 + e];
    v += bq * swv[b * 1536 + 768 + g * 48 + e] + bk * swv[b * 1536 + g * 48 + d]
         + 4096.f * bq * bk;
    red[0][i] = v * 0.015625f;                 // qscale = 4096^-0.5
  }
  __syncthreads();
  if (tid < 48) {
    const int d = tid;
    float m = -1e30f;
    for (int e = 0; e < 48; ++e) m = fmaxf(m, red[0][d * 48 + e]);
    float ssum = 0.f;
    for (int e = 0; e < 48; ++e) ssum += expf(red[0][d * 48 + e] - m);
    const float inv = 1.0f / ssum;
    for (int e = 0; e < 48; ++e)
      attn[(size_t)bg * 2304 + d * 48 + e] = expf(red[0][d * 48 + e] - m) * inv;
  }
}

// ---- block-diag: ao[b][n][g*48+d] = sum_e attn[bg][d][e] * v[bg][n][e] ----

__global__ __launch_bounds__(256) void blockdiag_kernel(const uint16_t* __restrict__ Vb,
                                                        const float* __restrict__ attn,
                                                        uint16_t* __restrict__ ao) {
  const int bg = blockIdx.x, ch = blockIdx.y;
  const int b = bg >> 4, g = bg & 15;
  const int tid = threadIdx.x;
  __shared__ uint16_t vs[128 * 64];
  __shared__ uint16_t as2[48 * 64];
  const size_t vbase = ((size_t)bg * 4096 + (size_t)ch * 128) * 48;
  const uint4* vg = (const uint4*)(Vb + vbase);
  for (int u = tid; u < 768; u += 256) {
    const int n = u / 6, c = u - n * 6;
    *(uint4*)(vs + n * 64 + c * 8) = vg[u];
  }
  {
    const int n = tid >> 1, c = 6 + (tid & 1);
    uint4 z; z.x = z.y = z.z = z.w = 0u;
    *(uint4*)(vs + n * 64 + c * 8) = z;
  }
  const float* ab = attn + (size_t)bg * 2304;
  for (int i = tid; i < 48 * 64; i += 256) {
    int d = i >> 6, e = i & 63;
    as2[i] = (e < 48) ? f2b(ab[d * 48 + e]) : (uint16_t)0;
  }
  __syncthreads();
  const int lane = tid & 63, w = tid >> 6;
  const int lrow = lane & 15, kb = lane >> 4;
  f32x4 acc[2][3] = {};
#pragma unroll
  for (int ksb = 0; ksb < 2; ++ksb) {
    short8 a[2], bb[3];
#pragma unroll
    for (int i = 0; i < 2; ++i)
      a[i] = *(const short8*)(vs + (w * 32 + i * 16 + lrow) * 64 + ksb * 32 + kb * 8);
#pragma unroll
    for (int c = 0; c < 3; ++c)
      bb[c] = *(const short8*)(as2 + (c * 16 + lrow) * 64 + ksb * 32 + kb * 8);
#pragma unroll
    for (int i = 0; i < 2; ++i)
#pragma unroll
      for (int c = 0; c < 3; ++c)
        acc[i][c] = __builtin_amdgcn_mfma_f32_16x16x32_bf16(a[i], bb[c], acc[i][c], 0, 0, 0);
  }
#pragma unroll
  for (int i = 0; i < 2; ++i)
#pragma unroll
    for (int c = 0; c < 3; ++c)
#pragma unroll
      for (int r = 0; r < 4; ++r) {
        const int nl = w * 32 + i * 16 + kb * 4 + r;
        const int dcol = c * 16 + lrow;
        const size_t row = (size_t)b * 4096 + (size_t)ch * 128 + nl;
        ao[row * 768 + g * 48 + dcol] = f2b(acc[i][c][r]);
      }
}

// ---- proj GEMM: out = ao @ wpT^T + b_proj, f32 out ----

__global__ __launch_bounds__(256) void projgemm_kernel(
    const uint16_t* __restrict__ A, const uint16_t* __restrict__ Bt,
    const float* __restrict__ bias, float* __restrict__ out) {
  __shared__ uint16_t As[128 * 32];
  __shared__ uint16_t Bs[128 * 32];
  const int tid = threadIdx.x;
  int wg = xcd_swizzle((int)blockIdx.x, 1536 / 8);
  const int mblk = wg / 6, nblk = wg % 6;
  const int m0 = mblk * 128, n0 = nblk * 128;

  f32x4 acc[4][4] = {};
  gemm2p_core<24>(A, 768, Bt, 768, m0, n0, tid, As, Bs, acc);

  const int lane = tid & 63, wid = tid >> 6;
  const int wr = wid >> 1, wc = wid & 1;
  const int lrow = lane & 15, kb = lane >> 4;
#pragma unroll
  for (int mf = 0; mf < 4; ++mf) {
    const int rowb = m0 + wr * 64 + mf * 16 + kb * 4;
#pragma unroll
    for (int nf = 0; nf < 4; ++nf) {
      const int col = n0 + wc * 64 + nf * 16 + lrow;
      const float bb = bias[col];
#pragma unroll
      for (int r = 0; r < 4; ++r)
        out[(size_t)(rowb + r) * 768 + col] = acc[mf][nf][r] + bb;
    }
  }
}

// ---------------- launcher ----------------

extern "C" void kernel_launch(void* const* d_in, const int* in_sizes, int n_in,
                              void* d_out, int out_size, void* d_ws, size_t ws_size,
                              hipStream_t stream) {
  const float* x      = (const float*)d_in[0];
  const float* w_qkv  = (const float*)d_in[1];
  const float* b_qkv  = (const float*)d_in[2];
  const float* w_proj = (const float*)d_in[3];
  const float* b_proj = (const float*)d_in[4];
  float* out = (float*)d_out;

  char* w = (char*)d_ws;
  uint16_t* xb  = (uint16_t*)w; w += (size_t)32768 * 768 * 2;     // 50.3 MB (reused as ao)
  uint16_t* wqT = (uint16_t*)w; w += (size_t)2304 * 768 * 2;      // 3.5 MB
  uint16_t* wpT = (uint16_t*)w; w += (size_t)768 * 768 * 2;       // 1.2 MB
  uint16_t* xt  = (uint16_t*)w; w += (size_t)8 * 768 * 4096 * 2;  // 50.3 MB
  uint16_t* Vb  = (uint16_t*)w; w += (size_t)128 * 4096 * 48 * 2; // 50.3 MB
  float*    G2  = (float*)w;    w += (size_t)2 * 8 * 768 * 768 * 4; // 37.7 MB
  uint16_t* G   = (uint16_t*)w; w += (size_t)8 * 768 * 768 * 2;   // 9.4 MB
  uint16_t* Tt  = (uint16_t*)w; w += (size_t)8 * 768 * 768 * 2;   // 9.4 MB
  float*    s   = (float*)w;    w += (size_t)8 * 768 * 4;         // 24 KB
  float*    swv = (float*)w;    w += (size_t)8 * 1536 * 4;        // 48 KB
  float*    attn= (float*)w;    w += (size_t)128 * 2304 * 4;      // 1.2 MB
  uint16_t* ao  = xb;   // xb dead after vgemm

  cast_xt_kernel<<<dim3(768, 8), 256, 0, stream>>>(x, xb, xt);
  transpose_cast_kernel<<<6912, 256, 0, stream>>>(w_qkv, wqT, 768, 2304);
  transpose_cast_kernel<<<2304, 256, 0, stream>>>(w_proj, wpT, 768, 768);
  vgemm_kernel<<<1536, 256, 0, stream>>>(xb, wqT + (size_t)1536 * 768, b_qkv, Vb);
  gram_kernel<<<576, 256, 0, stream>>>(xt, G2);
  reduceg_kernel<<<4608, 256, 0, stream>>>(G2, G);
  sb_kernel<<<24, 256, 0, stream>>>(xt, s);
  sw_kernel<<<48, 256, 0, stream>>>(s, wqT, swv);
  ttgemm_kernel<<<288, 256, 0, stream>>>(wqT + (size_t)768 * 768, G, Tt);
  logits48_kernel<<<128, 256, 0, stream>>>(wqT, Tt, swv, b_qkv, attn);
  blockdiag_kernel<<<dim3(128, 32), 256, 0, stream>>>(Vb, attn, ao);
  projgemm_kernel<<<1536, 256, 0, stream>>>(ao, wpT, b_proj, out);
}